// Round 16
// baseline (1245.737 us; speedup 1.0000x reference)
//
#include <hip/hip_runtime.h>

using u16 = unsigned short;
using u32 = unsigned int;

typedef __bf16 bf16x8 __attribute__((ext_vector_type(8)));
typedef float  f32x4  __attribute__((ext_vector_type(4)));
typedef u16    u16x8  __attribute__((ext_vector_type(8)));

static constexpr int kV = 32000, kH = 1024, kB = 64, kT = 64, kL = 4, kEOS = 2;

struct Flag { int v; int pad[15]; };   // one 64B line per flag

__device__ __forceinline__ u16 f2bf(float f) {
  u32 u = __float_as_uint(f);
  u = (u + 0x7fffu + ((u >> 16) & 1u)) >> 16;
  return (u16)u;
}
__device__ __forceinline__ float sigf(float x)   { return 1.0f / (1.0f + __expf(-x)); }
__device__ __forceinline__ float tanhf_(float x) { return 1.0f - 2.0f / (__expf(2.0f * x) + 1.0f); }

typedef const __attribute__((address_space(1))) u32* gas_ptr;
typedef __attribute__((address_space(3))) u32*       las_ptr;
__device__ __forceinline__ void async16(const u16* g, u16* l) {
  __builtin_amdgcn_global_load_lds((gas_ptr)g, (las_ptr)l, 16, 0, 0);
}

__device__ __forceinline__ void spin_ge(const int* p, int tgt) {
  while (__hip_atomic_load(p, __ATOMIC_RELAXED, __HIP_MEMORY_SCOPE_AGENT) < tgt)
    __builtin_amdgcn_s_sleep(2);
}

// Frag-packed 64x1024 bf16 matrix: [mtile=b>>4][ks=k>>5][lane=((k>>3)&3)*16+(b&15)][elem=k&7]
__device__ __forceinline__ size_t packed_off(int b, int k) {
  return (size_t)(((b >> 4) * 32 + (k >> 5)) * 512 + (((k >> 3) & 3) * 16 + (b & 15)) * 8 + (k & 7));
}

__device__ __forceinline__ u16x8 cvt8(const float* src) {
  const float4* s4 = (const float4*)src;
  float4 v0 = s4[0], v1 = s4[1];
  u16x8 r;
  r[0]=f2bf(v0.x); r[1]=f2bf(v0.y); r[2]=f2bf(v0.z); r[3]=f2bf(v0.w);
  r[4]=f2bf(v1.x); r[5]=f2bf(v1.y); r[6]=f2bf(v1.z); r[7]=f2bf(v1.w);
  return r;
}

// ---------------- prep kernels (round-15 LDS-bounce versions) ----------------

__global__ void __launch_bounds__(256)
pack_lstm(const float* __restrict__ Wih, const float* __restrict__ Whh,
          u16* __restrict__ wpack) {
  __shared__ u16 lds[64 * 136];
  const int bid = blockIdx.x;                   // 4096 = 256 * 2 * 8
  const int lblk = bid >> 4, mt = (bid >> 3) & 1, kkg = bid & 7;
  const int lay = lblk >> 6, cb = lblk & 63;
  const int tid = threadIdx.x;
  const float* W = mt ? Whh : Wih;
  {
    const int rid = tid >> 2, q = tid & 3;
    const int gr = (rid >> 4) * 1024 + cb * 16 + (rid & 15);
    const float* src = W + ((size_t)lay * 4096 + gr) * 1024 + kkg * 128 + q * 32;
    u16* dst = lds + rid * 136 + q * 32;
    #pragma unroll
    for (int it = 0; it < 4; ++it)
      *(u16x8*)(dst + it * 8) = cvt8(src + it * 8);
  }
  __syncthreads();
  const int cf = tid >> 6, lane = tid & 63;
  const int rid = cf * 16 + (lane & 15);
  const int l4o = (lane >> 4) * 8;
  #pragma unroll
  for (int kl = 0; kl < 4; ++kl) {
    const int kk = kkg * 4 + kl;
    const u16x8 v = *(const u16x8*)(lds + rid * 136 + kl * 32 + l4o);
    *(u16x8*)(wpack + ((size_t)lblk * 16384 + mt * 8192 + kk * 256 + cf * 64 + lane) * 8) = v;
  }
}

// wclsb[bn(250)][kk(32)][l4(4)][row(128)][8]
__global__ void __launch_bounds__(256)
pack_cls(const float* __restrict__ W, u16* __restrict__ o) {
  __shared__ u16 lds[128 * 136];
  const int bid = blockIdx.x;                   // 2000 = 250 * 8
  const int bn = bid >> 3, kkg = bid & 7;
  const int tid = threadIdx.x;
  {
    const int row = tid >> 1, half = tid & 1;
    const float* src = W + ((size_t)(bn * 128 + row)) * 1024 + kkg * 128 + half * 64;
    u16* dst = lds + row * 136 + half * 64;
    #pragma unroll
    for (int it = 0; it < 8; ++it)
      *(u16x8*)(dst + it * 8) = cvt8(src + it * 8);
  }
  __syncthreads();
  #pragma unroll
  for (int kl = 0; kl < 4; ++kl) {
    const int kk = kkg * 4 + kl;
    #pragma unroll
    for (int q = 0; q < 2; ++q) {
      const int p = tid + q * 256, row = p & 127, l4 = p >> 7;
      const u16x8 v = *(const u16x8*)(lds + row * 136 + kl * 32 + l4 * 8);
      *(u16x8*)(o + ((size_t)bn * 16384 + kk * 512 + p) * 8) = v;
    }
  }
}

__global__ void pack_x(const float* __restrict__ emb, const int* __restrict__ tgt,
                       u16* __restrict__ X) {
  const int cid = blockIdx.x * 256 + threadIdx.x;    // < 524,288
  const int kc = cid & 127, b = (cid >> 7) & 63, t = cid >> 13;
  const int tok = (t == 0) ? kEOS : tgt[b * 64 + t - 1];
  const u16x8 r = cvt8(emb + (size_t)tok * 1024 + kc * 8);
  *(u16x8*)(X + (size_t)t * 65536 + packed_off(b, kc * 8)) = r;
}

__global__ void pack_init(const float* __restrict__ h0, const float* __restrict__ bih,
                          const float* __restrict__ bhh, u16* __restrict__ hball,
                          float* __restrict__ bsum) {
  const int cid = blockIdx.x * 256 + threadIdx.x;    // grid = 192*256
  if (cid < 32768) {
    const int kc = cid & 127, row = cid >> 7;        // row = lay*64 + b
    const int lay = row >> 6, b = row & 63;
    const u16x8 r = cvt8(h0 + (size_t)cid * 8);
    *(u16x8*)(hball + (size_t)lay * 65 * 65536 + packed_off(b, kc * 8)) = r;
  } else {
    const int i = cid - 32768;   // < 16384
    bsum[i] = bih[i] + bhh[i];
  }
}

// ---------------- recurrence (round-14 structure + T5 setprio around MFMA) ----------------
__global__ void __launch_bounds__(1024, 4)
lstm_coop(const u16* __restrict__ wpack, const u16* __restrict__ xall,
          u16* __restrict__ hball, const float* __restrict__ bsum,
          const float* __restrict__ c0, float* __restrict__ outh, float* __restrict__ outc,
          Flag* flags) {
  __shared__ u16 stg[3][32][512];    // 96 KB
  __shared__ float Gc[2][64][80];    // 40 KB

  const int tid = threadIdx.x, lane = tid & 63, wave = tid >> 6;
  const int l15 = lane & 15, l4 = lane >> 4;
  const int cmat = wave >> 3, cwc = (wave >> 1) & 3, ckh = wave & 1;
  const int blk = blockIdx.x;
  const int lay = (blk >> 1) & 3;
  const int cb  = ((blk >> 3) << 1) | (blk & 1);
  const int u0 = cb << 4;
  const int ub = tid >> 4, uu = tid & 15;

  float creg = c0[((size_t)lay * 64 + ub) * 1024 + u0 + uu];
  float bsv[4];
  #pragma unroll
  for (int g = 0; g < 4; ++g) bsv[g] = bsum[lay * 4096 + g * 1024 + u0 + uu];

  const size_t wbase = (size_t)(lay * 64 + cb) * 131072;
  bf16x8 breg[16];
  #pragma unroll
  for (int j = 0; j < 16; ++j)
    breg[j] = *(const bf16x8*)(wpack + wbase
        + (size_t)(((cmat * 32 + 2 * j + ckh) * 4) + cwc) * 512 + lane * 8);

  const int j0 = wave * 2, j1 = wave * 2 + 1;
  const int m2a = j0 >> 4, mta = (j0 >> 2) & 3, ksla = j0 & 3;
  const int m2b = j1 >> 4, mtb = (j1 >> 2) & 3, kslb = j1 & 3;

  u16* hlay = hball + (size_t)lay * 65 * 65536;
  const u16* hprev = (lay == 0) ? xall : (hball + (size_t)(lay - 1) * 65 * 65536);

  #pragma unroll 1
  for (int t = 0; t < kT; ++t) {
    if (t > 0 && tid < 64)                 spin_ge(&flags[lay * 64 + tid].v, t);
    if (lay > 0 && tid >= 64 && tid < 128) spin_ge(&flags[(lay - 1) * 64 + (tid - 64)].v, t + 1);
    __syncthreads();

    const u16* xsrc = (lay == 0) ? (xall + (size_t)t * 65536)
                                 : (hprev + (size_t)(t + 1) * 65536);
    const u16* hsrc = hlay + (size_t)t * 65536;

    const u16* ga = (m2a ? hsrc : xsrc) + (size_t)((mta * 32 + ksla) * 512) + lane * 8;
    const u16* gb = (m2b ? hsrc : xsrc) + (size_t)((mtb * 32 + kslb) * 512) + lane * 8;

    auto STAGE = [&](int c) {
      async16(ga + (size_t)c * 2048, &stg[c % 3][m2a * 16 + mta * 4 + ksla][0]);
      async16(gb + (size_t)c * 2048, &stg[c % 3][m2b * 16 + mtb * 4 + kslb][0]);
    };

    f32x4 acc[4] = {};
    STAGE(0); STAGE(1);
    #pragma unroll
    for (int c = 0; c < 8; ++c) {
      if (c < 7) asm volatile("s_waitcnt vmcnt(2)" ::: "memory");
      else       asm volatile("s_waitcnt vmcnt(0)" ::: "memory");
      __builtin_amdgcn_s_barrier();
      asm volatile("" ::: "memory");
      if (c < 6) STAGE(c + 2);
      const u16* As = &stg[c % 3][cmat * 16][0];
      __builtin_amdgcn_s_setprio(1);
      #pragma unroll
      for (int s = 0; s < 2; ++s) {
        const int ksl = 2 * s + ckh;
        bf16x8 a[4];
        #pragma unroll
        for (int m = 0; m < 4; ++m)
          a[m] = *(const bf16x8*)(As + (m * 4 + ksl) * 512 + lane * 8);
        #pragma unroll
        for (int m = 0; m < 4; ++m)
          acc[m] = __builtin_amdgcn_mfma_f32_16x16x32_bf16(a[m], breg[2 * c + s], acc[m], 0, 0, 0);
      }
      __builtin_amdgcn_s_setprio(0);
    }

    if (ckh == 0) {
      #pragma unroll
      for (int m = 0; m < 4; ++m)
        #pragma unroll
        for (int r = 0; r < 4; ++r)
          Gc[cmat][m * 16 + l4 * 4 + r][cwc * 16 + l15] = acc[m][r];
    }
    __syncthreads();
    if (ckh == 1) {
      #pragma unroll
      for (int m = 0; m < 4; ++m)
        #pragma unroll
        for (int r = 0; r < 4; ++r)
          Gc[cmat][m * 16 + l4 * 4 + r][cwc * 16 + l15] += acc[m][r];
    }
    __syncthreads();

    float sg[4];
    #pragma unroll
    for (int g = 0; g < 4; ++g) {
      const int col = g * 16 + uu;
      sg[g] = Gc[0][ub][col] + Gc[1][ub][col] + bsv[g];
    }
    const float c2 = sigf(sg[1]) * creg + sigf(sg[0]) * tanhf_(sg[2]);
    const float h2 = sigf(sg[3]) * tanhf_(c2);
    creg = c2;
    const u16 hv = f2bf(h2);
    if (t == kT - 1) {
      outh[((size_t)lay * 64 + ub) * 1024 + u0 + uu] = h2;
      outc[((size_t)lay * 64 + ub) * 1024 + u0 + uu] = c2;
    }
    const u32 other = __shfl_xor((u32)hv, 1);
    if ((tid & 1) == 0) {
      const u32 hpair = (u32)hv | (other << 16);
      u32* hdst = (u32*)(hlay + (size_t)(t + 1) * 65536 + packed_off(ub, u0 + uu));
      __hip_atomic_store(hdst, hpair, __ATOMIC_RELAXED, __HIP_MEMORY_SCOPE_AGENT);
    }
    __syncthreads();
    if (tid == 0)
      __hip_atomic_store(&flags[lay * 64 + cb].v, t + 1, __ATOMIC_RELAXED, __HIP_MEMORY_SCOPE_AGENT);
  }
}

// ---------------- classifier GEMM: 128x256 tile, 8 waves / 512 thr ----------------
// Ring-3 LDS = 3 x (A 8KB + B 16KB) = 72 KB -> 2 blocks/CU x 8 waves = 16 waves/CU
// (4/SIMD, up from 12/3). 4000 blocks (half), A re-read once per 256 cols.
// Per-kk: 24 x 1KB chunks staged (8 A + 16 B) = 3 loads/wave; counted vmcnt(3).
__global__ void __launch_bounds__(512, 4)
cls_gemm(const u16* __restrict__ A, const u16* __restrict__ Bw,
         const float* __restrict__ bcls, float* __restrict__ out,
         float* __restrict__ pmax, float* __restrict__ psum) {
  __shared__ u16 sA[3][4096], sB[3][8192];   // 24 + 48 KB
  const int tid = threadIdx.x, lane = tid & 63, wave = tid >> 6;
  const int wm = wave >> 2, wc = wave & 3;   // M half, N quarter
  const int l15 = lane & 15, l4 = lane >> 4;
  const int bm = blockIdx.x, bny = blockIdx.y;   // grid (32, 125), bm-fastest
  const int bn0 = bny * 2;
  const u16* Ab = A + (size_t)bm * 131072;

  auto STAGE = [&](int kk) {
    u16* dA = sA[kk % 3]; u16* dB = sB[kk % 3];
    #pragma unroll
    for (int q = 0; q < 3; ++q) {
      const int c = wave * 3 + q;
      if (c < 8) {        // A chunk: tq = c>>2, mtile = c&3
        const u16* g = Ab + (size_t)(c >> 2) * 65536 + (size_t)(((c & 3) * 32 + kk) * 512) + lane * 8;
        async16(g, dA + c * 512);
      } else {            // B chunk b = c-8: pan = b>>3, v = b&7
        const int b = c - 8, pan = b >> 3, v = b & 7;
        const u16* g = Bw + (size_t)(bn0 + pan) * 131072 + (size_t)kk * 4096 + v * 512 + lane * 8;
        async16(g, dB + pan * 4096 + v * 512);
      }
    }
  };

  f32x4 acc[4][4] = {};
  STAGE(0); STAGE(1);
  for (int kk = 0; kk < 32; ++kk) {
    if (kk < 31) asm volatile("s_waitcnt vmcnt(3)" ::: "memory");
    else         asm volatile("s_waitcnt vmcnt(0)" ::: "memory");
    __builtin_amdgcn_s_barrier();
    asm volatile("" ::: "memory");
    if (kk < 30) STAGE(kk + 2);
    const u16* aS = sA[kk % 3]; const u16* bS = sB[kk % 3];
    const int pan = wc >> 1, cbase = (wc & 1) * 64;
    bf16x8 av[4], bv[4];
    #pragma unroll
    for (int mi = 0; mi < 4; ++mi) av[mi] = *(const bf16x8*)(aS + (wm * 4 + mi) * 512 + lane * 8);
    #pragma unroll
    for (int ci = 0; ci < 4; ++ci)
      bv[ci] = *(const bf16x8*)(bS + pan * 4096 + l4 * 1024 + (cbase + ci * 16 + l15) * 8);
    #pragma unroll
    for (int mi = 0; mi < 4; ++mi)
      #pragma unroll
      for (int ci = 0; ci < 4; ++ci)
        acc[mi][ci] = __builtin_amdgcn_mfma_f32_16x16x32_bf16(av[mi], bv[ci], acc[mi][ci], 0, 0, 0);
  }
  float bc[4];
  #pragma unroll
  for (int ci = 0; ci < 4; ++ci) bc[ci] = bcls[bn0 * 128 + wc * 64 + ci * 16 + l15];
  #pragma unroll
  for (int ci = 0; ci < 4; ++ci) {
    const int col = bn0 * 128 + wc * 64 + ci * 16 + l15;
    #pragma unroll
    for (int mi = 0; mi < 4; ++mi)
      #pragma unroll
      for (int r = 0; r < 4; ++r) {
        const int row = bm * 128 + wm * 64 + mi * 16 + l4 * 4 + r;
        out[(size_t)row * 32000 + col] = acc[mi][ci][r] + bc[ci];
      }
  }
  __syncthreads();
  // fused row-stats: each wave's 64-col slice -> 4-way merge per row, per-128-panel out
  {
    float* sRm = (float*)&sA[0][0];   // [4][128]
    float* sRs = sRm + 512;
    #pragma unroll
    for (int mi = 0; mi < 4; ++mi) {
      #pragma unroll
      for (int r = 0; r < 4; ++r) {
        float v[4];
        #pragma unroll
        for (int ci = 0; ci < 4; ++ci) v[ci] = acc[mi][ci][r] + bc[ci];
        float mx = fmaxf(fmaxf(v[0], v[1]), fmaxf(v[2], v[3]));
        mx = fmaxf(mx, __shfl_xor(mx, 1)); mx = fmaxf(mx, __shfl_xor(mx, 2));
        mx = fmaxf(mx, __shfl_xor(mx, 4)); mx = fmaxf(mx, __shfl_xor(mx, 8));
        float ss = __expf(v[0]-mx) + __expf(v[1]-mx) + __expf(v[2]-mx) + __expf(v[3]-mx);
        ss += __shfl_xor(ss, 1); ss += __shfl_xor(ss, 2);
        ss += __shfl_xor(ss, 4); ss += __shfl_xor(ss, 8);
        const int lr = wm * 64 + mi * 16 + l4 * 4 + r;
        if (l15 == 0) { sRm[wc * 128 + lr] = mx; sRs[wc * 128 + lr] = ss; }
      }
    }
    __syncthreads();
    if (tid < 256) {
      const int pan = tid >> 7, row = tid & 127;
      const float m0 = sRm[(pan * 2) * 128 + row],     s0 = sRs[(pan * 2) * 128 + row];
      const float m1 = sRm[(pan * 2 + 1) * 128 + row], s1 = sRs[(pan * 2 + 1) * 128 + row];
      const float M = fmaxf(m0, m1);
      const float S = s0 * __expf(m0 - M) + s1 * __expf(m1 - M);
      pmax[(size_t)(bm * 128 + row) * 256 + (bn0 + pan)] = M;
      psum[(size_t)(bm * 128 + row) * 256 + (bn0 + pan)] = S;
    }
  }
}

// compact path (fallback; Bw f32 row-major, round-14 128x128 structure)
#define CLS_EPILOGUE_128()                                                                 \
  {                                                                                        \
    float* sRm = (float*)&sA[0][0];                                                        \
    float* sRs = sRm + 256;                                                                \
    _Pragma("unroll")                                                                      \
    for (int mi = 0; mi < 4; ++mi) {                                                       \
      _Pragma("unroll")                                                                    \
      for (int r = 0; r < 4; ++r) {                                                        \
        float v[4];                                                                        \
        _Pragma("unroll")                                                                  \
        for (int ci = 0; ci < 4; ++ci) v[ci] = acc[mi][ci][r] + bc[ci];                     \
        float mx = fmaxf(fmaxf(v[0], v[1]), fmaxf(v[2], v[3]));                            \
        mx = fmaxf(mx, __shfl_xor(mx, 1)); mx = fmaxf(mx, __shfl_xor(mx, 2));              \
        mx = fmaxf(mx, __shfl_xor(mx, 4)); mx = fmaxf(mx, __shfl_xor(mx, 8));              \
        float ss = __expf(v[0]-mx) + __expf(v[1]-mx) + __expf(v[2]-mx) + __expf(v[3]-mx);  \
        ss += __shfl_xor(ss, 1); ss += __shfl_xor(ss, 2);                                  \
        ss += __shfl_xor(ss, 4); ss += __shfl_xor(ss, 8);                                  \
        const int lr = wm * 64 + mi * 16 + l4 * 4 + r;                                     \
        if (l15 == 0) { sRm[wc * 128 + lr] = mx; sRs[wc * 128 + lr] = ss; }                \
      }                                                                                    \
    }                                                                                      \
    __syncthreads();                                                                       \
    if (tid < 128) {                                                                       \
      const float m0 = sRm[tid], s0 = sRs[tid];                                            \
      const float m1 = sRm[128 + tid], s1 = sRs[128 + tid];                                \
      const float M = fmaxf(m0, m1);                                                       \
      const float S = s0 * __expf(m0 - M) + s1 * __expf(m1 - M);                           \
      pmax[(size_t)(bm * 128 + tid) * 256 + bn] = M;                                       \
      psum[(size_t)(bm * 128 + tid) * 256 + bn] = S;                                       \
    }                                                                                      \
  }

__global__ void __launch_bounds__(256)
cls_gemm_f32(const u16* __restrict__ A, const float* __restrict__ Bw,
             const float* __restrict__ bcls, float* __restrict__ out,
             float* __restrict__ pmax, float* __restrict__ psum) {
  __shared__ u16 sA[3][4096], sB[3][4096];
  const int tid = threadIdx.x, lane = tid & 63, wave = tid >> 6;
  const int wm = wave >> 1, wc = wave & 1;
  const int l15 = lane & 15, l4 = lane >> 4;
  const int bm = blockIdx.x, bn = blockIdx.y;
  const u16*  Ab = A  + (size_t)bm * 131072;
  const float* Bb = Bw + (size_t)bn * 131072;

  auto LOADB = [&](int kk, u16x8* rb) {
    #pragma unroll
    for (int q = 0; q < 2; ++q) {
      const int p = tid + q * 256, row = p & 127, khi = p >> 7;
      rb[q] = cvt8(Bb + (size_t)row * 1024 + kk * 32 + khi * 8);
    }
  };
  auto WRITEB = [&](int kk, const u16x8* rb) {
    u16* dB = sB[kk % 3];
    #pragma unroll
    for (int q = 0; q < 2; ++q) {
      const int p = tid + q * 256, row = p & 127, khi = p >> 7;
      *(u16x8*)(dB + khi * 1024 + row * 8) = rb[q];
    }
  };
  auto STAGE_A = [&](int kk) {
    u16* dA = sA[kk % 3];
    #pragma unroll
    for (int q = 0; q < 2; ++q) {
      const int v = wave * 2 + q;
      const u16* g = Ab + (size_t)(v >> 2) * 65536 + (size_t)(((v & 3) * 32 + kk) * 512) + lane * 8;
      async16(g, dA + v * 512);
    }
  };

  f32x4 acc[4][4] = {};
  {
    u16x8 rb[2];
    LOADB(0, rb); STAGE_A(0); WRITEB(0, rb);
  }
  for (int kk = 0; kk < 32; ++kk) {
    if (kk < 31) {
      u16x8 rb[2];
      LOADB(kk + 1, rb);
      STAGE_A(kk + 1);
      WRITEB(kk + 1, rb);
    } else {
      asm volatile("s_waitcnt vmcnt(0)" ::: "memory");
    }
    __builtin_amdgcn_s_barrier();
    asm volatile("" ::: "memory");
    const u16* aS = sA[kk % 3]; const u16* bS = sB[kk % 3];
    bf16x8 av[4], bv[4];
    #pragma unroll
    for (int mi = 0; mi < 4; ++mi) av[mi] = *(const bf16x8*)(aS + (wm * 4 + mi) * 512 + lane * 8);
    #pragma unroll
    for (int ci = 0; ci < 4; ++ci) bv[ci] = *(const bf16x8*)(bS + l4 * 1024 + (wc * 64 + ci * 16 + l15) * 8);
    #pragma unroll
    for (int mi = 0; mi < 4; ++mi)
      #pragma unroll
      for (int ci = 0; ci < 4; ++ci)
        acc[mi][ci] = __builtin_amdgcn_mfma_f32_16x16x32_bf16(av[mi], bv[ci], acc[mi][ci], 0, 0, 0);
    asm volatile("" ::: "memory");
    __builtin_amdgcn_s_barrier();
  }
  float bc[4];
  #pragma unroll
  for (int ci = 0; ci < 4; ++ci) bc[ci] = bcls[bn * 128 + wc * 64 + ci * 16 + l15];
  #pragma unroll
  for (int ci = 0; ci < 4; ++ci) {
    const int col = bn * 128 + wc * 64 + ci * 16 + l15;
    #pragma unroll
    for (int mi = 0; mi < 4; ++mi)
      #pragma unroll
      for (int r = 0; r < 4; ++r) {
        const int row = bm * 128 + wm * 64 + mi * 16 + l4 * 4 + r;
        out[(size_t)row * 32000 + col] = acc[mi][ci][r] + bc[ci];
      }
  }
  __syncthreads();
  CLS_EPILOGUE_128()
}

// ---------------- fused softmax: merge partials + subtract ----------------
__global__ void __launch_bounds__(256)
lsm_sub(const float* __restrict__ pmax, const float* __restrict__ psum,
        float* __restrict__ out) {
  __shared__ float rm[256], rs[256];
  const int r = blockIdx.x, b = threadIdx.x;
  float m = -3.0e38f, s = 0.0f;
  if (b < 250) { m = pmax[(size_t)r * 256 + b]; s = psum[(size_t)r * 256 + b]; }
  rm[b] = m; rs[b] = s; __syncthreads();
  for (int st = 128; st > 0; st >>= 1) {
    if (b < st) {
      const float m2 = rm[b + st], s2 = rs[b + st];
      const float M = fmaxf(rm[b], m2);
      rs[b] = rs[b] * __expf(rm[b] - M) + s2 * __expf(m2 - M);
      rm[b] = M;
    }
    __syncthreads();
  }
  const float z = rm[0] + logf(rs[0]);
  float4* p = (float4*)(out + (size_t)r * 32000);
  for (int v = b; v < 8000; v += 256) {
    float4 x = p[v];
    x.x -= z; x.y -= z; x.z -= z; x.w -= z;
    p[v] = x;
  }
}

// ---------------- host ----------------
extern "C" void kernel_launch(void* const* d_in, const int* in_sizes, int n_in,
                              void* d_out, int out_size, void* d_ws, size_t ws_size,
                              hipStream_t stream) {
  (void)in_sizes; (void)n_in; (void)out_size;
  const int*   tgt  = (const int*)d_in[1];
  const float* h0   = (const float*)d_in[2];
  const float* c0   = (const float*)d_in[3];
  const float* emb  = (const float*)d_in[4];
  const float* Wih  = (const float*)d_in[5];
  const float* Whh  = (const float*)d_in[6];
  const float* bih  = (const float*)d_in[7];
  const float* bhh  = (const float*)d_in[8];
  const float* Wcls = (const float*)d_in[9];
  const float* bcls = (const float*)d_in[10];

  float* out  = (float*)d_out;
  float* outh = out + (size_t)kT * kB * kV;
  float* outc = outh + (size_t)kL * kB * kH;

  const size_t SZ_WPACK = 67108864;
  const size_t SZ_WCLS  = 65536000;
  const size_t SZ_X     = 8388608;
  const size_t SZ_HBALL = 34078720;   // L*65*B*H bf16
  const size_t SZ_BSUM  = 65536;
  const size_t SZ_FLAGS = 16384;
  const size_t SZ_PM    = 4194304;    // 4096*256 f32
  const size_t FULL_REQ = SZ_WPACK + SZ_WCLS + SZ_X + SZ_HBALL + SZ_BSUM + SZ_FLAGS + 2 * SZ_PM;
  const bool full = (ws_size >= FULL_REQ);

  char* ws = (char*)d_ws;
  size_t off = 0;
  u16* wpack = (u16*)(ws + off); off += SZ_WPACK;
  u16* wclsb = nullptr;
  if (full) { wclsb = (u16*)(ws + off); off += SZ_WCLS; }
  u16*   X     = (u16*)(ws + off); off += SZ_X;
  u16*   hball = (u16*)(ws + off); off += SZ_HBALL;
  float* bsum  = (float*)(ws + off); off += SZ_BSUM;
  Flag*  flags = (Flag*)(ws + off);  off += SZ_FLAGS;
  float* pmax  = (float*)(ws + off); off += SZ_PM;
  float* psum  = (float*)(ws + off); off += SZ_PM;

  pack_lstm<<<4096, 256, 0, stream>>>(Wih, Whh, wpack);
  if (full) pack_cls<<<2000, 256, 0, stream>>>(Wcls, wclsb);
  pack_x   <<<2048,  256, 0, stream>>>(emb, tgt, X);
  pack_init<<<192,   256, 0, stream>>>(h0, bih, bhh, hball, bsum);
  hipMemsetAsync(flags, 0, SZ_FLAGS, stream);

  void* args[] = { (void*)&wpack, (void*)&X, (void*)&hball, (void*)&bsum,
                   (void*)&c0, (void*)&outh, (void*)&outc, (void*)&flags };
  hipLaunchCooperativeKernel((const void*)lstm_coop, dim3(256), dim3(1024), args, 0, stream);

  const u16* h3a = hball + (size_t)3 * 65 * 65536 + 65536;
  if (full) cls_gemm    <<<dim3(32, 125), 512, 0, stream>>>(h3a, wclsb, bcls, out, pmax, psum);
  else      cls_gemm_f32<<<dim3(32, 250), 256, 0, stream>>>(h3a, Wcls,  bcls, out, pmax, psum);
  lsm_sub<<<4096, 256, 0, stream>>>(pmax, psum, out);
}

// Round 17
// 1187.521 us; speedup vs baseline: 1.0490x; 1.0490x over previous
//
#include <hip/hip_runtime.h>

using u16 = unsigned short;
using u32 = unsigned int;

typedef __bf16 bf16x8 __attribute__((ext_vector_type(8)));
typedef float  f32x4  __attribute__((ext_vector_type(4)));
typedef u16    u16x8  __attribute__((ext_vector_type(8)));

static constexpr int kV = 32000, kH = 1024, kB = 64, kT = 64, kL = 4, kEOS = 2;

struct Flag { int v; int pad[15]; };   // one 64B line per flag

__device__ __forceinline__ u16 f2bf(float f) {
  u32 u = __float_as_uint(f);
  u = (u + 0x7fffu + ((u >> 16) & 1u)) >> 16;
  return (u16)u;
}
__device__ __forceinline__ float sigf(float x)   { return 1.0f / (1.0f + __expf(-x)); }
__device__ __forceinline__ float tanhf_(float x) { return 1.0f - 2.0f / (__expf(2.0f * x) + 1.0f); }

typedef const __attribute__((address_space(1))) u32* gas_ptr;
typedef __attribute__((address_space(3))) u32*       las_ptr;
__device__ __forceinline__ void async16(const u16* g, u16* l) {
  __builtin_amdgcn_global_load_lds((gas_ptr)g, (las_ptr)l, 16, 0, 0);
}

__device__ __forceinline__ void spin_ge(const int* p, int tgt) {
  while (__hip_atomic_load(p, __ATOMIC_RELAXED, __HIP_MEMORY_SCOPE_AGENT) < tgt)
    __builtin_amdgcn_s_sleep(2);
}

// Frag-packed 64x1024 bf16 matrix: [mtile=b>>4][ks=k>>5][lane=((k>>3)&3)*16+(b&15)][elem=k&7]
__device__ __forceinline__ size_t packed_off(int b, int k) {
  return (size_t)(((b >> 4) * 32 + (k >> 5)) * 512 + (((k >> 3) & 3) * 16 + (b & 15)) * 8 + (k & 7));
}

__device__ __forceinline__ u16x8 cvt8(const float* src) {
  const float4* s4 = (const float4*)src;
  float4 v0 = s4[0], v1 = s4[1];
  u16x8 r;
  r[0]=f2bf(v0.x); r[1]=f2bf(v0.y); r[2]=f2bf(v0.z); r[3]=f2bf(v0.w);
  r[4]=f2bf(v1.x); r[5]=f2bf(v1.y); r[6]=f2bf(v1.z); r[7]=f2bf(v1.w);
  return r;
}

// ---------------- prep kernels (LDS-bounce versions) ----------------

__global__ void __launch_bounds__(256)
pack_lstm(const float* __restrict__ Wih, const float* __restrict__ Whh,
          u16* __restrict__ wpack) {
  __shared__ u16 lds[64 * 136];
  const int bid = blockIdx.x;                   // 4096 = 256 * 2 * 8
  const int lblk = bid >> 4, mt = (bid >> 3) & 1, kkg = bid & 7;
  const int lay = lblk >> 6, cb = lblk & 63;
  const int tid = threadIdx.x;
  const float* W = mt ? Whh : Wih;
  {
    const int rid = tid >> 2, q = tid & 3;
    const int gr = (rid >> 4) * 1024 + cb * 16 + (rid & 15);
    const float* src = W + ((size_t)lay * 4096 + gr) * 1024 + kkg * 128 + q * 32;
    u16* dst = lds + rid * 136 + q * 32;
    #pragma unroll
    for (int it = 0; it < 4; ++it)
      *(u16x8*)(dst + it * 8) = cvt8(src + it * 8);
  }
  __syncthreads();
  const int cf = tid >> 6, lane = tid & 63;
  const int rid = cf * 16 + (lane & 15);
  const int l4o = (lane >> 4) * 8;
  #pragma unroll
  for (int kl = 0; kl < 4; ++kl) {
    const int kk = kkg * 4 + kl;
    const u16x8 v = *(const u16x8*)(lds + rid * 136 + kl * 32 + l4o);
    *(u16x8*)(wpack + ((size_t)lblk * 16384 + mt * 8192 + kk * 256 + cf * 64 + lane) * 8) = v;
  }
}

// wclsb[bn(250)][kk(32)][l4(4)][row(128)][8]
__global__ void __launch_bounds__(256)
pack_cls(const float* __restrict__ W, u16* __restrict__ o) {
  __shared__ u16 lds[128 * 136];
  const int bid = blockIdx.x;                   // 2000 = 250 * 8
  const int bn = bid >> 3, kkg = bid & 7;
  const int tid = threadIdx.x;
  {
    const int row = tid >> 1, half = tid & 1;
    const float* src = W + ((size_t)(bn * 128 + row)) * 1024 + kkg * 128 + half * 64;
    u16* dst = lds + row * 136 + half * 64;
    #pragma unroll
    for (int it = 0; it < 8; ++it)
      *(u16x8*)(dst + it * 8) = cvt8(src + it * 8);
  }
  __syncthreads();
  #pragma unroll
  for (int kl = 0; kl < 4; ++kl) {
    const int kk = kkg * 4 + kl;
    #pragma unroll
    for (int q = 0; q < 2; ++q) {
      const int p = tid + q * 256, row = p & 127, l4 = p >> 7;
      const u16x8 v = *(const u16x8*)(lds + row * 136 + kl * 32 + l4 * 8);
      *(u16x8*)(o + ((size_t)bn * 16384 + kk * 512 + p) * 8) = v;
    }
  }
}

__global__ void pack_x(const float* __restrict__ emb, const int* __restrict__ tgt,
                       u16* __restrict__ X) {
  const int cid = blockIdx.x * 256 + threadIdx.x;    // < 524,288
  const int kc = cid & 127, b = (cid >> 7) & 63, t = cid >> 13;
  const int tok = (t == 0) ? kEOS : tgt[b * 64 + t - 1];
  const u16x8 r = cvt8(emb + (size_t)tok * 1024 + kc * 8);
  *(u16x8*)(X + (size_t)t * 65536 + packed_off(b, kc * 8)) = r;
}

__global__ void pack_init(const float* __restrict__ h0, const float* __restrict__ bih,
                          const float* __restrict__ bhh, u16* __restrict__ hball,
                          float* __restrict__ bsum) {
  const int cid = blockIdx.x * 256 + threadIdx.x;    // grid = 192*256
  if (cid < 32768) {
    const int kc = cid & 127, row = cid >> 7;        // row = lay*64 + b
    const int lay = row >> 6, b = row & 63;
    const u16x8 r = cvt8(h0 + (size_t)cid * 8);
    *(u16x8*)(hball + (size_t)lay * 65 * 65536 + packed_off(b, kc * 8)) = r;
  } else {
    const int i = cid - 32768;   // < 16384
    bsum[i] = bih[i] + bhh[i];
  }
}

// ---------------- recurrence (structure at floor; unchanged) ----------------
__global__ void __launch_bounds__(1024, 4)
lstm_coop(const u16* __restrict__ wpack, const u16* __restrict__ xall,
          u16* __restrict__ hball, const float* __restrict__ bsum,
          const float* __restrict__ c0, float* __restrict__ outh, float* __restrict__ outc,
          Flag* flags) {
  __shared__ u16 stg[3][32][512];    // 96 KB
  __shared__ float Gc[2][64][80];    // 40 KB

  const int tid = threadIdx.x, lane = tid & 63, wave = tid >> 6;
  const int l15 = lane & 15, l4 = lane >> 4;
  const int cmat = wave >> 3, cwc = (wave >> 1) & 3, ckh = wave & 1;
  const int blk = blockIdx.x;
  const int lay = (blk >> 1) & 3;
  const int cb  = ((blk >> 3) << 1) | (blk & 1);
  const int u0 = cb << 4;
  const int ub = tid >> 4, uu = tid & 15;

  float creg = c0[((size_t)lay * 64 + ub) * 1024 + u0 + uu];
  float bsv[4];
  #pragma unroll
  for (int g = 0; g < 4; ++g) bsv[g] = bsum[lay * 4096 + g * 1024 + u0 + uu];

  const size_t wbase = (size_t)(lay * 64 + cb) * 131072;
  bf16x8 breg[16];
  #pragma unroll
  for (int j = 0; j < 16; ++j)
    breg[j] = *(const bf16x8*)(wpack + wbase
        + (size_t)(((cmat * 32 + 2 * j + ckh) * 4) + cwc) * 512 + lane * 8);

  const int j0 = wave * 2, j1 = wave * 2 + 1;
  const int m2a = j0 >> 4, mta = (j0 >> 2) & 3, ksla = j0 & 3;
  const int m2b = j1 >> 4, mtb = (j1 >> 2) & 3, kslb = j1 & 3;

  u16* hlay = hball + (size_t)lay * 65 * 65536;
  const u16* hprev = (lay == 0) ? xall : (hball + (size_t)(lay - 1) * 65 * 65536);

  #pragma unroll 1
  for (int t = 0; t < kT; ++t) {
    if (t > 0 && tid < 64)                 spin_ge(&flags[lay * 64 + tid].v, t);
    if (lay > 0 && tid >= 64 && tid < 128) spin_ge(&flags[(lay - 1) * 64 + (tid - 64)].v, t + 1);
    __syncthreads();

    const u16* xsrc = (lay == 0) ? (xall + (size_t)t * 65536)
                                 : (hprev + (size_t)(t + 1) * 65536);
    const u16* hsrc = hlay + (size_t)t * 65536;

    const u16* ga = (m2a ? hsrc : xsrc) + (size_t)((mta * 32 + ksla) * 512) + lane * 8;
    const u16* gb = (m2b ? hsrc : xsrc) + (size_t)((mtb * 32 + kslb) * 512) + lane * 8;

    auto STAGE = [&](int c) {
      async16(ga + (size_t)c * 2048, &stg[c % 3][m2a * 16 + mta * 4 + ksla][0]);
      async16(gb + (size_t)c * 2048, &stg[c % 3][m2b * 16 + mtb * 4 + kslb][0]);
    };

    f32x4 acc[4] = {};
    STAGE(0); STAGE(1);
    #pragma unroll
    for (int c = 0; c < 8; ++c) {
      if (c < 7) asm volatile("s_waitcnt vmcnt(2)" ::: "memory");
      else       asm volatile("s_waitcnt vmcnt(0)" ::: "memory");
      __builtin_amdgcn_s_barrier();
      asm volatile("" ::: "memory");
      if (c < 6) STAGE(c + 2);
      const u16* As = &stg[c % 3][cmat * 16][0];
      __builtin_amdgcn_s_setprio(1);
      #pragma unroll
      for (int s = 0; s < 2; ++s) {
        const int ksl = 2 * s + ckh;
        bf16x8 a[4];
        #pragma unroll
        for (int m = 0; m < 4; ++m)
          a[m] = *(const bf16x8*)(As + (m * 4 + ksl) * 512 + lane * 8);
        #pragma unroll
        for (int m = 0; m < 4; ++m)
          acc[m] = __builtin_amdgcn_mfma_f32_16x16x32_bf16(a[m], breg[2 * c + s], acc[m], 0, 0, 0);
      }
      __builtin_amdgcn_s_setprio(0);
    }

    if (ckh == 0) {
      #pragma unroll
      for (int m = 0; m < 4; ++m)
        #pragma unroll
        for (int r = 0; r < 4; ++r)
          Gc[cmat][m * 16 + l4 * 4 + r][cwc * 16 + l15] = acc[m][r];
    }
    __syncthreads();
    if (ckh == 1) {
      #pragma unroll
      for (int m = 0; m < 4; ++m)
        #pragma unroll
        for (int r = 0; r < 4; ++r)
          Gc[cmat][m * 16 + l4 * 4 + r][cwc * 16 + l15] += acc[m][r];
    }
    __syncthreads();

    float sg[4];
    #pragma unroll
    for (int g = 0; g < 4; ++g) {
      const int col = g * 16 + uu;
      sg[g] = Gc[0][ub][col] + Gc[1][ub][col] + bsv[g];
    }
    const float c2 = sigf(sg[1]) * creg + sigf(sg[0]) * tanhf_(sg[2]);
    const float h2 = sigf(sg[3]) * tanhf_(c2);
    creg = c2;
    const u16 hv = f2bf(h2);
    if (t == kT - 1) {
      outh[((size_t)lay * 64 + ub) * 1024 + u0 + uu] = h2;
      outc[((size_t)lay * 64 + ub) * 1024 + u0 + uu] = c2;
    }
    const u32 other = __shfl_xor((u32)hv, 1);
    if ((tid & 1) == 0) {
      const u32 hpair = (u32)hv | (other << 16);
      u32* hdst = (u32*)(hlay + (size_t)(t + 1) * 65536 + packed_off(ub, u0 + uu));
      __hip_atomic_store(hdst, hpair, __ATOMIC_RELAXED, __HIP_MEMORY_SCOPE_AGENT);
    }
    __syncthreads();
    if (tid == 0)
      __hip_atomic_store(&flags[lay * 64 + cb].v, t + 1, __ATOMIC_RELAXED, __HIP_MEMORY_SCOPE_AGENT);
  }
}

// ---------------- classifier GEMM: 128x256 tile, 8 waves / 512 thr ----------------
// Writes logits as bf16 into the FIRST HALF of each out-row's f32 slot
// (row r bf16 at u16 index r*64000 + col); lsm_sub expands to f32 in place.
__global__ void __launch_bounds__(512, 4)
cls_gemm(const u16* __restrict__ A, const u16* __restrict__ Bw,
         const float* __restrict__ bcls, float* __restrict__ out,
         float* __restrict__ pmax, float* __restrict__ psum) {
  __shared__ u16 sA[3][4096], sB[3][8192];   // 24 + 48 KB
  const int tid = threadIdx.x, lane = tid & 63, wave = tid >> 6;
  const int wm = wave >> 2, wc = wave & 3;   // M half, N quarter
  const int l15 = lane & 15, l4 = lane >> 4;
  const int bm = blockIdx.x, bny = blockIdx.y;   // grid (32, 125), bm-fastest
  const int bn0 = bny * 2;
  const u16* Ab = A + (size_t)bm * 131072;

  auto STAGE = [&](int kk) {
    u16* dA = sA[kk % 3]; u16* dB = sB[kk % 3];
    #pragma unroll
    for (int q = 0; q < 3; ++q) {
      const int c = wave * 3 + q;
      if (c < 8) {
        const u16* g = Ab + (size_t)(c >> 2) * 65536 + (size_t)(((c & 3) * 32 + kk) * 512) + lane * 8;
        async16(g, dA + c * 512);
      } else {
        const int b = c - 8, pan = b >> 3, v = b & 7;
        const u16* g = Bw + (size_t)(bn0 + pan) * 131072 + (size_t)kk * 4096 + v * 512 + lane * 8;
        async16(g, dB + pan * 4096 + v * 512);
      }
    }
  };

  f32x4 acc[4][4] = {};
  STAGE(0); STAGE(1);
  for (int kk = 0; kk < 32; ++kk) {
    if (kk < 31) asm volatile("s_waitcnt vmcnt(3)" ::: "memory");
    else         asm volatile("s_waitcnt vmcnt(0)" ::: "memory");
    __builtin_amdgcn_s_barrier();
    asm volatile("" ::: "memory");
    if (kk < 30) STAGE(kk + 2);
    const u16* aS = sA[kk % 3]; const u16* bS = sB[kk % 3];
    const int pan = wc >> 1, cbase = (wc & 1) * 64;
    bf16x8 av[4], bv[4];
    #pragma unroll
    for (int mi = 0; mi < 4; ++mi) av[mi] = *(const bf16x8*)(aS + (wm * 4 + mi) * 512 + lane * 8);
    #pragma unroll
    for (int ci = 0; ci < 4; ++ci)
      bv[ci] = *(const bf16x8*)(bS + pan * 4096 + l4 * 1024 + (cbase + ci * 16 + l15) * 8);
    #pragma unroll
    for (int mi = 0; mi < 4; ++mi)
      #pragma unroll
      for (int ci = 0; ci < 4; ++ci)
        acc[mi][ci] = __builtin_amdgcn_mfma_f32_16x16x32_bf16(av[mi], bv[ci], acc[mi][ci], 0, 0, 0);
  }
  float bc[4];
  #pragma unroll
  for (int ci = 0; ci < 4; ++ci) bc[ci] = bcls[bn0 * 128 + wc * 64 + ci * 16 + l15];
  // bf16 logits, lane-paired u32 stores
  u16* lb = (u16*)out;
  #pragma unroll
  for (int ci = 0; ci < 4; ++ci) {
    const int col = bn0 * 128 + wc * 64 + ci * 16 + l15;
    #pragma unroll
    for (int mi = 0; mi < 4; ++mi)
      #pragma unroll
      for (int r = 0; r < 4; ++r) {
        const int row = bm * 128 + wm * 64 + mi * 16 + l4 * 4 + r;
        const u16 v = f2bf(acc[mi][ci][r] + bc[ci]);
        const u32 other = __shfl_xor((u32)v, 1);
        if ((l15 & 1) == 0)
          *(u32*)(lb + (size_t)row * 64000 + col) = (u32)v | (other << 16);
      }
  }
  __syncthreads();
  // fused row-stats: each wave's 64-col slice -> 4-way merge per row, per-128-panel out
  {
    float* sRm = (float*)&sA[0][0];   // [4][128]
    float* sRs = sRm + 512;
    #pragma unroll
    for (int mi = 0; mi < 4; ++mi) {
      #pragma unroll
      for (int r = 0; r < 4; ++r) {
        float v[4];
        #pragma unroll
        for (int ci = 0; ci < 4; ++ci) v[ci] = acc[mi][ci][r] + bc[ci];
        float mx = fmaxf(fmaxf(v[0], v[1]), fmaxf(v[2], v[3]));
        mx = fmaxf(mx, __shfl_xor(mx, 1)); mx = fmaxf(mx, __shfl_xor(mx, 2));
        mx = fmaxf(mx, __shfl_xor(mx, 4)); mx = fmaxf(mx, __shfl_xor(mx, 8));
        float ss = __expf(v[0]-mx) + __expf(v[1]-mx) + __expf(v[2]-mx) + __expf(v[3]-mx);
        ss += __shfl_xor(ss, 1); ss += __shfl_xor(ss, 2);
        ss += __shfl_xor(ss, 4); ss += __shfl_xor(ss, 8);
        const int lr = wm * 64 + mi * 16 + l4 * 4 + r;
        if (l15 == 0) { sRm[wc * 128 + lr] = mx; sRs[wc * 128 + lr] = ss; }
      }
    }
    __syncthreads();
    if (tid < 256) {
      const int pan = tid >> 7, row = tid & 127;
      const float m0 = sRm[(pan * 2) * 128 + row],     s0 = sRs[(pan * 2) * 128 + row];
      const float m1 = sRm[(pan * 2 + 1) * 128 + row], s1 = sRs[(pan * 2 + 1) * 128 + row];
      const float M = fmaxf(m0, m1);
      const float S = s0 * __expf(m0 - M) + s1 * __expf(m1 - M);
      pmax[(size_t)(bm * 128 + row) * 256 + (bn0 + pan)] = M;
      psum[(size_t)(bm * 128 + row) * 256 + (bn0 + pan)] = S;
    }
  }
}

// compact path (fallback; Bw f32 row-major, 128x128) — same bf16-logit output format
__global__ void __launch_bounds__(256)
cls_gemm_f32(const u16* __restrict__ A, const float* __restrict__ Bw,
             const float* __restrict__ bcls, float* __restrict__ out,
             float* __restrict__ pmax, float* __restrict__ psum) {
  __shared__ u16 sA[3][4096], sB[3][4096];
  const int tid = threadIdx.x, lane = tid & 63, wave = tid >> 6;
  const int wm = wave >> 1, wc = wave & 1;
  const int l15 = lane & 15, l4 = lane >> 4;
  const int bm = blockIdx.x, bn = blockIdx.y;
  const u16*  Ab = A  + (size_t)bm * 131072;
  const float* Bb = Bw + (size_t)bn * 131072;

  auto LOADB = [&](int kk, u16x8* rb) {
    #pragma unroll
    for (int q = 0; q < 2; ++q) {
      const int p = tid + q * 256, row = p & 127, khi = p >> 7;
      rb[q] = cvt8(Bb + (size_t)row * 1024 + kk * 32 + khi * 8);
    }
  };
  auto WRITEB = [&](int kk, const u16x8* rb) {
    u16* dB = sB[kk % 3];
    #pragma unroll
    for (int q = 0; q < 2; ++q) {
      const int p = tid + q * 256, row = p & 127, khi = p >> 7;
      *(u16x8*)(dB + khi * 1024 + row * 8) = rb[q];
    }
  };
  auto STAGE_A = [&](int kk) {
    u16* dA = sA[kk % 3];
    #pragma unroll
    for (int q = 0; q < 2; ++q) {
      const int v = wave * 2 + q;
      const u16* g = Ab + (size_t)(v >> 2) * 65536 + (size_t)(((v & 3) * 32 + kk) * 512) + lane * 8;
      async16(g, dA + v * 512);
    }
  };

  f32x4 acc[4][4] = {};
  {
    u16x8 rb[2];
    LOADB(0, rb); STAGE_A(0); WRITEB(0, rb);
  }
  for (int kk = 0; kk < 32; ++kk) {
    if (kk < 31) {
      u16x8 rb[2];
      LOADB(kk + 1, rb);
      STAGE_A(kk + 1);
      WRITEB(kk + 1, rb);
    } else {
      asm volatile("s_waitcnt vmcnt(0)" ::: "memory");
    }
    __builtin_amdgcn_s_barrier();
    asm volatile("" ::: "memory");
    const u16* aS = sA[kk % 3]; const u16* bS = sB[kk % 3];
    bf16x8 av[4], bv[4];
    #pragma unroll
    for (int mi = 0; mi < 4; ++mi) av[mi] = *(const bf16x8*)(aS + (wm * 4 + mi) * 512 + lane * 8);
    #pragma unroll
    for (int ci = 0; ci < 4; ++ci) bv[ci] = *(const bf16x8*)(bS + l4 * 1024 + (wc * 64 + ci * 16 + l15) * 8);
    #pragma unroll
    for (int mi = 0; mi < 4; ++mi)
      #pragma unroll
      for (int ci = 0; ci < 4; ++ci)
        acc[mi][ci] = __builtin_amdgcn_mfma_f32_16x16x32_bf16(av[mi], bv[ci], acc[mi][ci], 0, 0, 0);
    asm volatile("" ::: "memory");
    __builtin_amdgcn_s_barrier();
  }
  float bc[4];
  #pragma unroll
  for (int ci = 0; ci < 4; ++ci) bc[ci] = bcls[bn * 128 + wc * 64 + ci * 16 + l15];
  u16* lb = (u16*)out;
  #pragma unroll
  for (int ci = 0; ci < 4; ++ci) {
    const int col = bn * 128 + wc * 64 + ci * 16 + l15;
    #pragma unroll
    for (int mi = 0; mi < 4; ++mi)
      #pragma unroll
      for (int r = 0; r < 4; ++r) {
        const int row = bm * 128 + wm * 64 + mi * 16 + l4 * 4 + r;
        const u16 v = f2bf(acc[mi][ci][r] + bc[ci]);
        const u32 other = __shfl_xor((u32)v, 1);
        if ((l15 & 1) == 0)
          *(u32*)(lb + (size_t)row * 64000 + col) = (u32)v | (other << 16);
      }
  }
  __syncthreads();
  {
    float* sRm = (float*)&sA[0][0];
    float* sRs = sRm + 256;
    #pragma unroll
    for (int mi = 0; mi < 4; ++mi) {
      #pragma unroll
      for (int r = 0; r < 4; ++r) {
        float v[4];
        #pragma unroll
        for (int ci = 0; ci < 4; ++ci) v[ci] = acc[mi][ci][r] + bc[ci];
        float mx = fmaxf(fmaxf(v[0], v[1]), fmaxf(v[2], v[3]));
        mx = fmaxf(mx, __shfl_xor(mx, 1)); mx = fmaxf(mx, __shfl_xor(mx, 2));
        mx = fmaxf(mx, __shfl_xor(mx, 4)); mx = fmaxf(mx, __shfl_xor(mx, 8));
        float ss = __expf(v[0]-mx) + __expf(v[1]-mx) + __expf(v[2]-mx) + __expf(v[3]-mx);
        ss += __shfl_xor(ss, 1); ss += __shfl_xor(ss, 2);
        ss += __shfl_xor(ss, 4); ss += __shfl_xor(ss, 8);
        const int lr = wm * 64 + mi * 16 + l4 * 4 + r;
        if (l15 == 0) { sRm[wc * 128 + lr] = mx; sRs[wc * 128 + lr] = ss; }
      }
    }
    __syncthreads();
    if (tid < 128) {
      const float m0 = sRm[tid], s0 = sRs[tid];
      const float m1 = sRm[128 + tid], s1 = sRs[128 + tid];
      const float M = fmaxf(m0, m1);
      const float S = s0 * __expf(m0 - M) + s1 * __expf(m1 - M);
      pmax[(size_t)(bm * 128 + tid) * 256 + bn] = M;
      psum[(size_t)(bm * 128 + tid) * 256 + bn] = S;
    }
  }
}

// ---------------- fused softmax: bf16 row -> LDS, merge partials, f32 row out ----------------
__global__ void __launch_bounds__(256)
lsm_sub(const float* __restrict__ pmax, const float* __restrict__ psum,
        float* __restrict__ out) {
  __shared__ float rm[256], rs[256];
  __shared__ u16 rowbuf[32000];            // 62.5 KB
  const int r = blockIdx.x, b = threadIdx.x;
  const u16* lb = (const u16*)out;
  // copy this row's bf16 logits to LDS (global reads complete before first barrier)
  for (int j = b; j < 4000; j += 256)
    *(u16x8*)(rowbuf + j * 8) = *(const u16x8*)(lb + (size_t)r * 64000 + j * 8);
  float m = -3.0e38f, s = 0.0f;
  if (b < 250) { m = pmax[(size_t)r * 256 + b]; s = psum[(size_t)r * 256 + b]; }
  rm[b] = m; rs[b] = s; __syncthreads();
  for (int st = 128; st > 0; st >>= 1) {
    if (b < st) {
      const float m2 = rm[b + st], s2 = rs[b + st];
      const float M = fmaxf(rm[b], m2);
      rs[b] = rs[b] * __expf(rm[b] - M) + s2 * __expf(m2 - M);
      rm[b] = M;
    }
    __syncthreads();
  }
  const float z = rm[0] + logf(rs[0]);
  float* po = out + (size_t)r * 32000;
  for (int j = b; j < 4000; j += 256) {
    const u16x8 v = *(const u16x8*)(rowbuf + j * 8);
    float4 o0, o1;
    o0.x = __uint_as_float((u32)v[0] << 16) - z;
    o0.y = __uint_as_float((u32)v[1] << 16) - z;
    o0.z = __uint_as_float((u32)v[2] << 16) - z;
    o0.w = __uint_as_float((u32)v[3] << 16) - z;
    o1.x = __uint_as_float((u32)v[4] << 16) - z;
    o1.y = __uint_as_float((u32)v[5] << 16) - z;
    o1.z = __uint_as_float((u32)v[6] << 16) - z;
    o1.w = __uint_as_float((u32)v[7] << 16) - z;
    *(float4*)(po + j * 8)     = o0;
    *(float4*)(po + j * 8 + 4) = o1;
  }
}

// ---------------- host ----------------
extern "C" void kernel_launch(void* const* d_in, const int* in_sizes, int n_in,
                              void* d_out, int out_size, void* d_ws, size_t ws_size,
                              hipStream_t stream) {
  (void)in_sizes; (void)n_in; (void)out_size;
  const int*   tgt  = (const int*)d_in[1];
  const float* h0   = (const float*)d_in[2];
  const float* c0   = (const float*)d_in[3];
  const float* emb  = (const float*)d_in[4];
  const float* Wih  = (const float*)d_in[5];
  const float* Whh  = (const float*)d_in[6];
  const float* bih  = (const float*)d_in[7];
  const float* bhh  = (const float*)d_in[8];
  const float* Wcls = (const float*)d_in[9];
  const float* bcls = (const float*)d_in[10];

  float* out  = (float*)d_out;
  float* outh = out + (size_t)kT * kB * kV;
  float* outc = outh + (size_t)kL * kB * kH;

  const size_t SZ_WPACK = 67108864;
  const size_t SZ_WCLS  = 65536000;
  const size_t SZ_X     = 8388608;
  const size_t SZ_HBALL = 34078720;   // L*65*B*H bf16
  const size_t SZ_BSUM  = 65536;
  const size_t SZ_FLAGS = 16384;
  const size_t SZ_PM    = 4194304;    // 4096*256 f32
  const size_t FULL_REQ = SZ_WPACK + SZ_WCLS + SZ_X + SZ_HBALL + SZ_BSUM + SZ_FLAGS + 2 * SZ_PM;
  const bool full = (ws_size >= FULL_REQ);

  char* ws = (char*)d_ws;
  size_t off = 0;
  u16* wpack = (u16*)(ws + off); off += SZ_WPACK;
  u16* wclsb = nullptr;
  if (full) { wclsb = (u16*)(ws + off); off += SZ_WCLS; }
  u16*   X     = (u16*)(ws + off); off += SZ_X;
  u16*   hball = (u16*)(ws + off); off += SZ_HBALL;
  float* bsum  = (float*)(ws + off); off += SZ_BSUM;
  Flag*  flags = (Flag*)(ws + off);  off += SZ_FLAGS;
  float* pmax  = (float*)(ws + off); off += SZ_PM;
  float* psum  = (float*)(ws + off); off += SZ_PM;

  pack_lstm<<<4096, 256, 0, stream>>>(Wih, Whh, wpack);
  if (full) pack_cls<<<2000, 256, 0, stream>>>(Wcls, wclsb);
  pack_x   <<<2048,  256, 0, stream>>>(emb, tgt, X);
  pack_init<<<192,   256, 0, stream>>>(h0, bih, bhh, hball, bsum);
  hipMemsetAsync(flags, 0, SZ_FLAGS, stream);

  void* args[] = { (void*)&wpack, (void*)&X, (void*)&hball, (void*)&bsum,
                   (void*)&c0, (void*)&outh, (void*)&outc, (void*)&flags };
  hipLaunchCooperativeKernel((const void*)lstm_coop, dim3(256), dim3(1024), args, 0, stream);

  const u16* h3a = hball + (size_t)3 * 65 * 65536 + 65536;
  if (full) cls_gemm    <<<dim3(32, 125), 512, 0, stream>>>(h3a, wclsb, bcls, out, pmax, psum);
  else      cls_gemm_f32<<<dim3(32, 250), 256, 0, stream>>>(h3a, Wcls,  bcls, out, pmax, psum);
  lsm_sub<<<4096, 256, 0, stream>>>(pmax, psum, out);
}